// Round 1
// baseline (329.228 us; speedup 1.0000x reference)
//
#include <hip/hip_runtime.h>

typedef unsigned short u16;
typedef unsigned int   u32;
typedef unsigned char  u8;

using bf16x8 = __attribute__((ext_vector_type(8))) __bf16;
using f32x4  = __attribute__((ext_vector_type(4))) float;

__device__ __forceinline__ u16 f2bf(float f) {
    u32 u = __float_as_uint(f);
    return (u16)((u + 0x7FFFu + ((u >> 16) & 1u)) >> 16);
}

#define MFMA(a, b, c) __builtin_amdgcn_mfma_f32_16x16x32_bf16((a), (b), (c), 0, 0, 0)

// ---------------------------------------------------------------------------
// Wt[n][k] = bf16(W[k][n]), N = K = 1280
// ---------------------------------------------------------------------------
__global__ __launch_bounds__(256) void wtrans_kernel(const float* __restrict__ W,
                                                     u16* __restrict__ Wt) {
    const int N = 1280;
    __shared__ float t[32][33];
    const int bx = blockIdx.x * 32, by = blockIdx.y * 32;
    const int x = threadIdx.x, ty = threadIdx.y;
#pragma unroll
    for (int j = 0; j < 4; j++) {
        const int y = ty + j * 8;
        t[y][x] = W[(size_t)(by + y) * N + (bx + x)];
    }
    __syncthreads();
#pragma unroll
    for (int j = 0; j < 4; j++) {
        const int y = ty + j * 8;
        Wt[(size_t)(bx + y) * N + (by + x)] = f2bf(t[x][y]);
    }
}

// ---------------------------------------------------------------------------
// C[M,N] = A[M,K] @ Bt[N,K]^T.  A fp32 (cast on the fly) or bf16. Bt bf16.
// EPI: C fp32 = acc + bias[n] + resid[m,n];  else C bf16.
// BM=BN=128, BK=64, 256 threads (4 waves, each 64x64 out).
// LDS rows padded to 72 u16 (144B): conflict-free b128 access.
// ---------------------------------------------------------------------------
template <bool ABF16, bool EPI>
__global__ __launch_bounds__(256) void gemm_kernel(
    const void* __restrict__ Ap, const u16* __restrict__ Bt, void* __restrict__ Cp,
    const float* __restrict__ bias, const float* __restrict__ resid,
    const int M, const int N, const int K) {
    __shared__ __align__(16) u16 Al[128][72];
    __shared__ __align__(16) u16 Bl[128][72];
    const int tid = threadIdx.x;
    const int lane = tid & 63, w = tid >> 6;
    const int wr = w >> 1, wc = w & 1;
    const int lr = lane & 15, lq = lane >> 4;
    const int m0 = blockIdx.y * 128, n0 = blockIdx.x * 128;

    const f32x4 fzero = {0.f, 0.f, 0.f, 0.f};
    f32x4 acc[4][4];
#pragma unroll
    for (int i = 0; i < 4; i++)
#pragma unroll
        for (int j = 0; j < 4; j++) acc[i][j] = fzero;

    const int nkt = K >> 6;
    for (int kt = 0; kt < nkt; kt++) {
        const int k0 = kt << 6;
        __syncthreads();
#pragma unroll
        for (int i = 0; i < 4; i++) {
            const int id = i * 256 + tid;
            const int r = id >> 3, c = (id & 7) << 3;
            if (ABF16) {
                const u16* A = (const u16*)Ap;
                *(uint4*)&Al[r][c] = *(const uint4*)&A[(size_t)(m0 + r) * K + k0 + c];
            } else {
                const float* A = (const float*)Ap;
                const float4 f0 = *(const float4*)&A[(size_t)(m0 + r) * K + k0 + c];
                const float4 f1 = *(const float4*)&A[(size_t)(m0 + r) * K + k0 + c + 4];
                union { uint4 u; u16 s[8]; } cv;
                cv.s[0] = f2bf(f0.x); cv.s[1] = f2bf(f0.y);
                cv.s[2] = f2bf(f0.z); cv.s[3] = f2bf(f0.w);
                cv.s[4] = f2bf(f1.x); cv.s[5] = f2bf(f1.y);
                cv.s[6] = f2bf(f1.z); cv.s[7] = f2bf(f1.w);
                *(uint4*)&Al[r][c] = cv.u;
            }
            *(uint4*)&Bl[r][c] = *(const uint4*)&Bt[(size_t)(n0 + r) * K + k0 + c];
        }
        __syncthreads();
#pragma unroll
        for (int ks = 0; ks < 2; ks++) {
            bf16x8 af[4], bfv[4];
#pragma unroll
            for (int mi = 0; mi < 4; mi++)
                af[mi] = *(const bf16x8*)&Al[wr * 64 + mi * 16 + lr][ks * 32 + lq * 8];
#pragma unroll
            for (int ni = 0; ni < 4; ni++)
                bfv[ni] = *(const bf16x8*)&Bl[wc * 64 + ni * 16 + lr][ks * 32 + lq * 8];
#pragma unroll
            for (int mi = 0; mi < 4; mi++)
#pragma unroll
                for (int ni = 0; ni < 4; ni++)
                    acc[mi][ni] = MFMA(af[mi], bfv[ni], acc[mi][ni]);
        }
    }
#pragma unroll
    for (int mi = 0; mi < 4; mi++)
#pragma unroll
        for (int ni = 0; ni < 4; ni++)
#pragma unroll
            for (int j = 0; j < 4; j++) {
                const int row = m0 + wr * 64 + mi * 16 + lq * 4 + j;
                const int col = n0 + wc * 64 + ni * 16 + lr;
                const float v = acc[mi][ni][j];
                if (EPI) {
                    ((float*)Cp)[(size_t)row * N + col] =
                        v + bias[col] + resid[(size_t)row * N + col];
                } else {
                    ((u16*)Cp)[(size_t)row * N + col] = f2bf(v);
                }
            }
}

// ---------------------------------------------------------------------------
// Flash attention with seg_corr hard mask on the second half of keys.
// B=2,H=8,L=1024,S=2048,D=160. Block: (qtile=64 rows) x h x b, 4 waves.
// Wave w owns q-rows [w*16, w*16+16). K-tile = 64 keys. Online softmax.
// ---------------------------------------------------------------------------
__global__ __launch_bounds__(256) void attn_kernel(
    const u16* __restrict__ qb, const u16* __restrict__ kb, const u16* __restrict__ vb,
    const int* __restrict__ seg, u16* __restrict__ ao) {
    const int L = 1024, S = 2048, C = 1280, D = 160;
    __shared__ __align__(16) u16 Kl[64][168];   // keys row-major, +8 pad
    __shared__ __align__(16) u16 Vt[160][72];   // V transposed [d][key], +8 pad
    __shared__ __align__(16) u16 Pl[64][72];    // P (per-wave private rows)
    __shared__ u8 segl[16][256];                // seg_corr slice for this q-tile

    const int tid = threadIdx.x;
    const int lane = tid & 63, w = tid >> 6;
    const int lr = lane & 15, lq = lane >> 4;
    const int qt = blockIdx.x, h = blockIdx.y, bz = blockIdx.z;

#pragma unroll
    for (int i = 0; i < 16; i++) {
        const int id = i * 256 + tid;
        segl[id >> 8][id & 255] =
            (u8)seg[(size_t)(bz * 256 + qt * 16 + (id >> 8)) * 256 + (id & 255)];
    }

    // Q fragments hoisted to registers (A-operand: row = lane&15, k contiguous)
    bf16x8 qf[5];
    {
        const size_t grow = (size_t)(bz * L + qt * 64 + w * 16 + lr) * C + h * D;
#pragma unroll
        for (int ks = 0; ks < 5; ks++)
            qf[ks] = *(const bf16x8*)&qb[grow + ks * 32 + lq * 8];
    }

    float m_i[4], l_i[4];
#pragma unroll
    for (int j = 0; j < 4; j++) { m_i[j] = -1e30f; l_i[j] = 0.f; }
    const f32x4 fzero = {0.f, 0.f, 0.f, 0.f};
    f32x4 oacc[10];
#pragma unroll
    for (int d = 0; d < 10; d++) oacc[d] = fzero;

    int srow[5], scol[5];
#pragma unroll
    for (int i = 0; i < 5; i++) {
        const int id = i * 256 + tid;
        srow[i] = id / 20;
        scol[i] = (id % 20) * 8;
    }
    uint4 kreg[5], vreg[5];
#pragma unroll
    for (int i = 0; i < 5; i++) {
        const size_t g = (size_t)(bz * S + srow[i]) * C + h * D + scol[i];
        kreg[i] = *(const uint4*)&kb[g];
        vreg[i] = *(const uint4*)&vb[g];
    }
    const float sc = 0.07905694150420949f;  // 1/sqrt(160)

    for (int kt = 0; kt < 32; kt++) {
        __syncthreads();  // previous tile's compute done -> LDS reusable
#pragma unroll
        for (int i = 0; i < 5; i++) {
            *(uint4*)&Kl[srow[i]][scol[i]] = kreg[i];
            union { uint4 u; u16 s[8]; } cv; cv.u = vreg[i];
#pragma unroll
            for (int jj = 0; jj < 8; jj++) Vt[scol[i] + jj][srow[i]] = cv.s[jj];
        }
        __syncthreads();
        if (kt + 1 < 32) {  // prefetch next tile: latency hides under compute
#pragma unroll
            for (int i = 0; i < 5; i++) {
                const size_t g =
                    (size_t)(bz * S + (kt + 1) * 64 + srow[i]) * C + h * D + scol[i];
                kreg[i] = *(const uint4*)&kb[g];
                vreg[i] = *(const uint4*)&vb[g];
            }
        }

        // S = Q K^T for this wave's 16 q-rows x 64 keys
        f32x4 s4[4];
#pragma unroll
        for (int nt = 0; nt < 4; nt++) {
            s4[nt] = fzero;
#pragma unroll
            for (int ks = 0; ks < 5; ks++) {
                const bf16x8 bk = *(const bf16x8*)&Kl[nt * 16 + lr][ks * 32 + lq * 8];
                s4[nt] = MFMA(qf[ks], bk, s4[nt]);
            }
        }

        // scale + mask. D-layout: row = w*16 + lq*4 + j, col = nt*16 + lr.
        // rows are 4-aligned per (w,lq) -> one seg row per lane; mask uniform in j.
        const int q4 = w * 4 + lq;
        float p[4][4];
#pragma unroll
        for (int nt = 0; nt < 4; nt++) {
            float msk = 0.f;
            if (kt >= 16) {
                const int sg = (kt - 16) * 64 + nt * 16 + lr;
                if (!segl[q4][sg >> 2]) msk = -1e30f;
            }
#pragma unroll
            for (int j = 0; j < 4; j++) p[nt][j] = s4[nt][j] * sc + msk;
        }

        // online softmax (row reduce across the 16-lane col groups)
#pragma unroll
        for (int j = 0; j < 4; j++) {
            float rm = fmaxf(fmaxf(p[0][j], p[1][j]), fmaxf(p[2][j], p[3][j]));
            rm = fmaxf(rm, __shfl_xor(rm, 1));
            rm = fmaxf(rm, __shfl_xor(rm, 2));
            rm = fmaxf(rm, __shfl_xor(rm, 4));
            rm = fmaxf(rm, __shfl_xor(rm, 8));
            const float mn = fmaxf(m_i[j], rm);
            const float al = __expf(m_i[j] - mn);
            float sum = 0.f;
#pragma unroll
            for (int nt = 0; nt < 4; nt++) {
                const float e = __expf(p[nt][j] - mn);
                p[nt][j] = e;
                sum += e;
            }
            sum += __shfl_xor(sum, 1);
            sum += __shfl_xor(sum, 2);
            sum += __shfl_xor(sum, 4);
            sum += __shfl_xor(sum, 8);
            l_i[j] = l_i[j] * al + sum;
            m_i[j] = mn;
#pragma unroll
            for (int d = 0; d < 10; d++) oacc[d][j] *= al;
        }

        // P -> LDS (wave-private rows; same-wave ds ordering via lgkmcnt)
#pragma unroll
        for (int nt = 0; nt < 4; nt++)
#pragma unroll
            for (int j = 0; j < 4; j++)
                Pl[w * 16 + lq * 4 + j][nt * 16 + lr] = f2bf(p[nt][j]);

        // O += P @ V
        bf16x8 pa[2];
#pragma unroll
        for (int ks2 = 0; ks2 < 2; ks2++)
            pa[ks2] = *(const bf16x8*)&Pl[w * 16 + lr][ks2 * 32 + lq * 8];
#pragma unroll
        for (int nt2 = 0; nt2 < 10; nt2++)
#pragma unroll
            for (int ks2 = 0; ks2 < 2; ks2++) {
                const bf16x8 bv = *(const bf16x8*)&Vt[nt2 * 16 + lr][ks2 * 32 + lq * 8];
                oacc[nt2] = MFMA(pa[ks2], bv, oacc[nt2]);
            }
    }

#pragma unroll
    for (int nt2 = 0; nt2 < 10; nt2++)
#pragma unroll
        for (int j = 0; j < 4; j++) {
            const int row = qt * 64 + w * 16 + lq * 4 + j;
            const int col = h * D + nt2 * 16 + lr;
            ao[(size_t)(bz * L + row) * C + col] = f2bf(oacc[nt2][j] / l_i[j]);
        }
}

// ---------------------------------------------------------------------------
extern "C" void kernel_launch(void* const* d_in, const int* in_sizes, int n_in,
                              void* d_out, int out_size, void* d_ws, size_t ws_size,
                              hipStream_t stream) {
    const float* hs  = (const float*)d_in[0];
    const float* ehs = (const float*)d_in[1];
    const int*   seg = (const int*)d_in[2];
    const float* Wq  = (const float*)d_in[3];
    const float* Wk  = (const float*)d_in[4];
    const float* Wv  = (const float*)d_in[5];
    const float* Wo  = (const float*)d_in[6];
    const float* bo  = (const float*)d_in[7];
    float* out = (float*)d_out;

    const size_t WSZ = 1280u * 1280u;       // 1,638,400 u16
    const size_t QSZ = 2u * 1024u * 1280u;  // 2,621,440 u16
    const size_t KSZ = 2u * 2048u * 1280u;  // 5,242,880 u16
    u16* WqT  = (u16*)d_ws;
    u16* WkT  = WqT + WSZ;
    u16* WvT  = WkT + WSZ;
    u16* WoT  = WvT + WSZ;
    u16* qbuf = WoT + WSZ;
    u16* kbuf = qbuf + QSZ;
    u16* vbuf = kbuf + KSZ;
    u16* aobuf = vbuf + KSZ;
    // total ws use = 44,564,480 bytes

    dim3 tb(32, 8), tg(40, 40);
    wtrans_kernel<<<tg, tb, 0, stream>>>(Wq, WqT);
    wtrans_kernel<<<tg, tb, 0, stream>>>(Wk, WkT);
    wtrans_kernel<<<tg, tb, 0, stream>>>(Wv, WvT);
    wtrans_kernel<<<tg, tb, 0, stream>>>(Wo, WoT);

    gemm_kernel<false, false><<<dim3(10, 16), 256, 0, stream>>>(
        hs, WqT, qbuf, nullptr, nullptr, 2048, 1280, 1280);
    gemm_kernel<false, false><<<dim3(10, 32), 256, 0, stream>>>(
        ehs, WkT, kbuf, nullptr, nullptr, 4096, 1280, 1280);
    gemm_kernel<false, false><<<dim3(10, 32), 256, 0, stream>>>(
        ehs, WvT, vbuf, nullptr, nullptr, 4096, 1280, 1280);

    attn_kernel<<<dim3(16, 8, 2), 256, 0, stream>>>(qbuf, kbuf, vbuf, seg, aobuf);

    gemm_kernel<true, true><<<dim3(10, 16), 256, 0, stream>>>(
        aobuf, WoT, out, bo, hs, 2048, 1280, 1280);
}

// Round 2
// 256.792 us; speedup vs baseline: 1.2821x; 1.2821x over previous
//
#include <hip/hip_runtime.h>

typedef unsigned short u16;
typedef unsigned int   u32;
typedef unsigned char  u8;

using bf16x8 = __attribute__((ext_vector_type(8))) __bf16;
using f32x4  = __attribute__((ext_vector_type(4))) float;

__device__ __forceinline__ u16 f2bf(float f) {
    u32 u = __float_as_uint(f);
    return (u16)((u + 0x7FFFu + ((u >> 16) & 1u)) >> 16);
}

#define MFMA(a, b, c) __builtin_amdgcn_mfma_f32_16x16x32_bf16((a), (b), (c), 0, 0, 0)

// ---------------------------------------------------------------------------
// Wt[n][k] = bf16(W[k][n]) for 4 weights in one launch. N = K = 1280.
// ---------------------------------------------------------------------------
__global__ __launch_bounds__(256) void wtrans_kernel(
    const float* __restrict__ W0, const float* __restrict__ W1,
    const float* __restrict__ W2, const float* __restrict__ W3,
    u16* __restrict__ T0, u16* __restrict__ T1,
    u16* __restrict__ T2, u16* __restrict__ T3) {
    const int N = 1280;
    const int z = blockIdx.z;
    const float* W = (z == 0) ? W0 : (z == 1) ? W1 : (z == 2) ? W2 : W3;
    u16* T = (z == 0) ? T0 : (z == 1) ? T1 : (z == 2) ? T2 : T3;
    __shared__ float t[32][33];
    const int bx = blockIdx.x * 32, by = blockIdx.y * 32;
    const int x = threadIdx.x, ty = threadIdx.y;
#pragma unroll
    for (int j = 0; j < 4; j++) {
        const int y = ty + j * 8;
        t[y][x] = W[(size_t)(by + y) * N + (bx + x)];
    }
    __syncthreads();
#pragma unroll
    for (int j = 0; j < 4; j++) {
        const int y = ty + j * 8;
        T[(size_t)(bx + y) * N + (by + x)] = f2bf(t[x][y]);
    }
}

// ---------------------------------------------------------------------------
// C[M,N] = A[M,K] @ Bt[N,K]^T.  A fp32 (cast on the fly) or bf16. Bt bf16.
// EPI: C fp32 = acc + bias[n] + resid[m,n];  else C bf16.
// BM = MI*32, BN=128, BK=64, 256 threads (4 waves, each (MI*16)x64 out).
// LDS rows padded to 72 u16 (144B): conflict-free b128 access.
// ---------------------------------------------------------------------------
template <int MI, bool ABF16, bool EPI>
__global__ __launch_bounds__(256) void gemm_kernel(
    const void* __restrict__ Ap, const u16* __restrict__ Bt, void* __restrict__ Cp,
    const float* __restrict__ bias, const float* __restrict__ resid,
    const int M, const int N, const int K) {
    __shared__ __align__(16) u16 Al[MI * 32][72];
    __shared__ __align__(16) u16 Bl[128][72];
    const int tid = threadIdx.x;
    const int lane = tid & 63, w = tid >> 6;
    const int wr = w >> 1, wc = w & 1;
    const int lr = lane & 15, lq = lane >> 4;
    const int m0 = blockIdx.y * (MI * 32), n0 = blockIdx.x * 128;

    const f32x4 fzero = {0.f, 0.f, 0.f, 0.f};
    f32x4 acc[MI][4];
#pragma unroll
    for (int i = 0; i < MI; i++)
#pragma unroll
        for (int j = 0; j < 4; j++) acc[i][j] = fzero;

    const int nkt = K >> 6;
    for (int kt = 0; kt < nkt; kt++) {
        const int k0 = kt << 6;
        __syncthreads();
#pragma unroll
        for (int i = 0; i < MI; i++) {
            const int id = i * 256 + tid;
            const int r = id >> 3, c = (id & 7) << 3;
            if (ABF16) {
                const u16* A = (const u16*)Ap;
                *(uint4*)&Al[r][c] = *(const uint4*)&A[(size_t)(m0 + r) * K + k0 + c];
            } else {
                const float* A = (const float*)Ap;
                const float4 f0 = *(const float4*)&A[(size_t)(m0 + r) * K + k0 + c];
                const float4 f1 = *(const float4*)&A[(size_t)(m0 + r) * K + k0 + c + 4];
                union { uint4 u; u16 s[8]; } cv;
                cv.s[0] = f2bf(f0.x); cv.s[1] = f2bf(f0.y);
                cv.s[2] = f2bf(f0.z); cv.s[3] = f2bf(f0.w);
                cv.s[4] = f2bf(f1.x); cv.s[5] = f2bf(f1.y);
                cv.s[6] = f2bf(f1.z); cv.s[7] = f2bf(f1.w);
                *(uint4*)&Al[r][c] = cv.u;
            }
        }
#pragma unroll
        for (int i = 0; i < 4; i++) {
            const int id = i * 256 + tid;
            const int r = id >> 3, c = (id & 7) << 3;
            *(uint4*)&Bl[r][c] = *(const uint4*)&Bt[(size_t)(n0 + r) * K + k0 + c];
        }
        __syncthreads();
#pragma unroll
        for (int ks = 0; ks < 2; ks++) {
            bf16x8 af[MI], bfv[4];
#pragma unroll
            for (int mi = 0; mi < MI; mi++)
                af[mi] = *(const bf16x8*)&Al[wr * (MI * 16) + mi * 16 + lr][ks * 32 + lq * 8];
#pragma unroll
            for (int ni = 0; ni < 4; ni++)
                bfv[ni] = *(const bf16x8*)&Bl[wc * 64 + ni * 16 + lr][ks * 32 + lq * 8];
#pragma unroll
            for (int mi = 0; mi < MI; mi++)
#pragma unroll
                for (int ni = 0; ni < 4; ni++)
                    acc[mi][ni] = MFMA(af[mi], bfv[ni], acc[mi][ni]);
        }
    }
#pragma unroll
    for (int mi = 0; mi < MI; mi++)
#pragma unroll
        for (int ni = 0; ni < 4; ni++)
#pragma unroll
            for (int j = 0; j < 4; j++) {
                const int row = m0 + wr * (MI * 16) + mi * 16 + lq * 4 + j;
                const int col = n0 + wc * 64 + ni * 16 + lr;
                const float v = acc[mi][ni][j];
                if (EPI) {
                    ((float*)Cp)[(size_t)row * N + col] =
                        v + bias[col] + resid[(size_t)row * N + col];
                } else {
                    ((u16*)Cp)[(size_t)row * N + col] = f2bf(v);
                }
            }
}

// ---------------------------------------------------------------------------
// Flash attention with seg_corr hard mask on the second half of keys.
// B=2,H=8,L=1024,S=2048,C=1280,D=160. Grid: (16 qtiles, 8 h, 2 b), 512 thr.
// 8 waves = 2 kv-groups of 4; group g processes kt = 2t+g (t=0..15), each
// wave owns 16 q-rows. Partial (m,l,O) merged through LDS overlay at end.
// V stored in LDS as [d][s] with chunk-XOR swizzle (conflict-free both ways).
// ---------------------------------------------------------------------------
__global__ __launch_bounds__(512) void attn_kernel(
    const u16* __restrict__ qb, const u16* __restrict__ kvb,
    const int* __restrict__ seg, u16* __restrict__ ao) {
    const int L = 1024, S = 2048, C = 1280;
    __shared__ __align__(16) u16 Kl[2][64][168];   // keys row-major, +8 pad
    __shared__ __align__(16) u16 VtF[2][160 * 64]; // V^T [d][s] chunk-swizzled
    __shared__ __align__(16) u16 Pl[2][64][72];    // P per group
    __shared__ u8 segl[16][256];

    const int tid = threadIdx.x;
    const int lane = tid & 63, w = tid >> 6;
    const int g = w >> 2, wi = w & 3;
    const int gtid = tid & 255;
    const int lr = lane & 15, lq = lane >> 4;
    const int qt = blockIdx.x, h = blockIdx.y, bz = blockIdx.z;

#pragma unroll
    for (int i = 0; i < 8; i++) {
        const int id = i * 512 + tid;
        segl[id >> 8][id & 255] =
            (u8)seg[(size_t)(bz * 256 + qt * 16 + (id >> 8)) * 256 + (id & 255)];
    }

    // Q fragments hoisted to registers
    bf16x8 qf[5];
    {
        const size_t grow = (size_t)(bz * L + qt * 64 + wi * 16 + lr) * C + h * 160;
#pragma unroll
        for (int ks = 0; ks < 5; ks++)
            qf[ks] = *(const bf16x8*)&qb[grow + ks * 32 + lq * 8];
    }

    // staging geometry (fixed per thread across tiles)
    int srow[5], scol[5], v8e[5];
#pragma unroll
    for (int i = 0; i < 5; i++) {
        const int id = i * 256 + gtid;
        srow[i] = id / 20;
        const int sc8 = id % 20;          // d-chunk index 0..19
        scol[i] = sc8 * 8;
        const int ci = (srow[i] >> 3) ^ (sc8 & 7);
        v8e[i] = sc8 * 512 + (srow[i] & 7) + ci * 8;  // element offset, jj-XOR walks
    }
    // V read addresses (element offsets into VtF[g]): d = nt2*16+lr, s-chunk swz
    int adrV[10][2];
#pragma unroll
    for (int nt2 = 0; nt2 < 10; nt2++)
#pragma unroll
        for (int ks2 = 0; ks2 < 2; ks2++) {
            const int d = nt2 * 16 + lr;
            const int swz = (ks2 * 4 + lq) ^ (d & 7) ^ ((d >> 3) & 7);
            adrV[nt2][ks2] = d * 64 + swz * 8;
        }

    float m_i[4], l_i[4];
#pragma unroll
    for (int j = 0; j < 4; j++) { m_i[j] = 0.f; l_i[j] = 0.f; }
    const f32x4 fzero = {0.f, 0.f, 0.f, 0.f};
    f32x4 oacc[10];
#pragma unroll
    for (int d = 0; d < 10; d++) oacc[d] = fzero;

    // prologue: load tile t=0 (kt = g)
    uint4 kreg[5], vreg[5];
#pragma unroll
    for (int i = 0; i < 5; i++) {
        const size_t gr = (size_t)(bz * S + g * 64 + srow[i]) * 2560 + h * 160 + scol[i];
        kreg[i] = *(const uint4*)&kvb[gr];
        vreg[i] = *(const uint4*)&kvb[gr + 1280];
    }
    const float sc = 0.07905694150420949f;  // 1/sqrt(160)

    for (int t = 0; t < 16; t++) {
        const int kt = 2 * t + g;
        __syncthreads();  // previous tile's compute done (all waves)
#pragma unroll
        for (int i = 0; i < 5; i++) {
            *(uint4*)&Kl[g][srow[i]][scol[i]] = kreg[i];
            union { uint4 u; u16 s[8]; } cv; cv.u = vreg[i];
#pragma unroll
            for (int jj = 0; jj < 8; jj++)
                VtF[g][(v8e[i] ^ (jj * 8)) + jj * 64] = cv.s[jj];
        }
        __syncthreads();
        if (t + 1 < 16) {  // prefetch next tile (hides under compute)
#pragma unroll
            for (int i = 0; i < 5; i++) {
                const size_t gr =
                    (size_t)(bz * S + (kt + 2) * 64 + srow[i]) * 2560 + h * 160 + scol[i];
                kreg[i] = *(const uint4*)&kvb[gr];
                vreg[i] = *(const uint4*)&kvb[gr + 1280];
            }
        }

        // S = Q K^T for this wave's 16 q-rows x 64 keys
        f32x4 s4[4];
#pragma unroll
        for (int nt = 0; nt < 4; nt++) {
            s4[nt] = fzero;
#pragma unroll
            for (int ks = 0; ks < 5; ks++) {
                const bf16x8 bk = *(const bf16x8*)&Kl[g][nt * 16 + lr][ks * 32 + lq * 8];
                s4[nt] = MFMA(qf[ks], bk, s4[nt]);
            }
        }

        // scale + mask. D-layout: row = wi*16 + lq*4 + j, col = nt*16 + lr.
        const int q4 = wi * 4 + lq;
        float p[4][4];
#pragma unroll
        for (int nt = 0; nt < 4; nt++) {
            float msk = 0.f;
            if (kt >= 16) {
                const int sg = (kt - 16) * 64 + nt * 16 + lr;
                if (!segl[q4][sg >> 2]) msk = -1e30f;
            }
#pragma unroll
            for (int j = 0; j < 4; j++) p[nt][j] = s4[nt][j] * sc + msk;
        }

        // online softmax with defer-max (THR=8; scores here are O(1))
#pragma unroll
        for (int j = 0; j < 4; j++) {
            float rm = fmaxf(fmaxf(p[0][j], p[1][j]), fmaxf(p[2][j], p[3][j]));
            rm = fmaxf(rm, __shfl_xor(rm, 1));
            rm = fmaxf(rm, __shfl_xor(rm, 2));
            rm = fmaxf(rm, __shfl_xor(rm, 4));
            rm = fmaxf(rm, __shfl_xor(rm, 8));
            if (__any(rm > m_i[j] + 8.f)) {
                const float mn = fmaxf(m_i[j], rm);
                const float al = __expf(m_i[j] - mn);
                l_i[j] *= al;
                m_i[j] = mn;
#pragma unroll
                for (int d = 0; d < 10; d++) oacc[d][j] *= al;
            }
            float sum = 0.f;
#pragma unroll
            for (int nt = 0; nt < 4; nt++) {
                const float e = __expf(p[nt][j] - m_i[j]);
                p[nt][j] = e;
                sum += e;
            }
            sum += __shfl_xor(sum, 1);
            sum += __shfl_xor(sum, 2);
            sum += __shfl_xor(sum, 4);
            sum += __shfl_xor(sum, 8);
            l_i[j] += sum;
        }

        // P -> LDS (wave-private rows)
#pragma unroll
        for (int nt = 0; nt < 4; nt++)
#pragma unroll
            for (int j = 0; j < 4; j++)
                Pl[g][wi * 16 + lq * 4 + j][nt * 16 + lr] = f2bf(p[nt][j]);

        // O += P @ V
        bf16x8 pa[2];
#pragma unroll
        for (int ks2 = 0; ks2 < 2; ks2++)
            pa[ks2] = *(const bf16x8*)&Pl[g][wi * 16 + lr][ks2 * 32 + lq * 8];
#pragma unroll
        for (int nt2 = 0; nt2 < 10; nt2++)
#pragma unroll
            for (int ks2 = 0; ks2 < 2; ks2++) {
                const bf16x8 bv = *(const bf16x8*)&VtF[g][adrV[nt2][ks2]];
                oacc[nt2] = MFMA(pa[ks2], bv, oacc[nt2]);
            }
    }

    // ---- merge group partials through LDS overlay ----
    __syncthreads();
    float* Of = (float*)&Kl[0][0][0];   // 64 x 164 fp32 (41984B <= 43008B)
    float* Ml = (float*)&VtF[0][0];     // 64 x {m,l}
    if (g == 1) {
        if (lr == 0) {
#pragma unroll
            for (int j = 0; j < 4; j++) {
                const int row = wi * 16 + lq * 4 + j;
                Ml[row * 2] = m_i[j];
                Ml[row * 2 + 1] = l_i[j];
            }
        }
#pragma unroll
        for (int nt2 = 0; nt2 < 10; nt2++)
#pragma unroll
            for (int j = 0; j < 4; j++)
                Of[(wi * 16 + lq * 4 + j) * 164 + nt2 * 16 + lr] = oacc[nt2][j];
    }
    __syncthreads();
    if (g == 0) {
#pragma unroll
        for (int j = 0; j < 4; j++) {
            const int row = wi * 16 + lq * 4 + j;
            const float m1 = Ml[row * 2], l1 = Ml[row * 2 + 1];
            const float mm = fmaxf(m_i[j], m1);
            const float a0 = __expf(m_i[j] - mm), a1 = __expf(m1 - mm);
            const float inv = 1.f / (l_i[j] * a0 + l1 * a1);
#pragma unroll
            for (int nt2 = 0; nt2 < 10; nt2++) {
                const float v =
                    (oacc[nt2][j] * a0 + Of[row * 164 + nt2 * 16 + lr] * a1) * inv;
                ao[(size_t)(bz * L + qt * 64 + row) * C + h * 160 + nt2 * 16 + lr] =
                    f2bf(v);
            }
        }
    }
}

// ---------------------------------------------------------------------------
extern "C" void kernel_launch(void* const* d_in, const int* in_sizes, int n_in,
                              void* d_out, int out_size, void* d_ws, size_t ws_size,
                              hipStream_t stream) {
    const float* hs  = (const float*)d_in[0];
    const float* ehs = (const float*)d_in[1];
    const int*   seg = (const int*)d_in[2];
    const float* Wq  = (const float*)d_in[3];
    const float* Wk  = (const float*)d_in[4];
    const float* Wv  = (const float*)d_in[5];
    const float* Wo  = (const float*)d_in[6];
    const float* bo  = (const float*)d_in[7];
    float* out = (float*)d_out;

    const size_t WSZ = 1280u * 1280u;        // 1,638,400 u16
    const size_t QSZ = 2u * 1024u * 1280u;   // 2,621,440 u16
    const size_t KVSZ = 4096u * 2560u;       // 10,485,760 u16
    u16* WqT   = (u16*)d_ws;
    u16* WkT   = WqT + WSZ;
    u16* WvT   = WkT + WSZ;   // contiguous after WkT -> merged KV GEMM
    u16* WoT   = WvT + WSZ;
    u16* qbuf  = WoT + WSZ;
    u16* kvbuf = qbuf + QSZ;
    u16* aobuf = kvbuf + KVSZ;
    // total ws use = 44,564,480 bytes

    dim3 tb(32, 8), tg(40, 40, 4);
    wtrans_kernel<<<tg, tb, 0, stream>>>(Wq, Wk, Wv, Wo, WqT, WkT, WvT, WoT);

    gemm_kernel<2, false, false><<<dim3(10, 32), 256, 0, stream>>>(
        hs, WqT, qbuf, nullptr, nullptr, 2048, 1280, 1280);
    gemm_kernel<4, false, false><<<dim3(20, 32), 256, 0, stream>>>(
        ehs, WkT, kvbuf, nullptr, nullptr, 4096, 2560, 1280);

    attn_kernel<<<dim3(16, 8, 2), 512, 0, stream>>>(qbuf, kvbuf, seg, aobuf);

    gemm_kernel<2, true, true><<<dim3(10, 32), 256, 0, stream>>>(
        aobuf, WoT, out, bo, hs, 2048, 1280, 1280);
}

// Round 3
// 246.865 us; speedup vs baseline: 1.3336x; 1.0402x over previous
//
#include <hip/hip_runtime.h>

typedef unsigned short u16;
typedef unsigned int   u32;
typedef unsigned char  u8;

using bf16x8 = __attribute__((ext_vector_type(8))) __bf16;
using f32x4  = __attribute__((ext_vector_type(4))) float;

__device__ __forceinline__ u16 f2bf(float f) {
    u32 u = __float_as_uint(f);
    return (u16)((u + 0x7FFFu + ((u >> 16) & 1u)) >> 16);
}
__device__ __forceinline__ float bf2f(u16 x) {
    return __uint_as_float(((u32)x) << 16);
}

#define MFMA(a, b, c) __builtin_amdgcn_mfma_f32_16x16x32_bf16((a), (b), (c), 0, 0, 0)

// async global->LDS 16B: per-lane global source, wave-uniform LDS base + lane*16
__device__ __forceinline__ void gll16(const u16* g, u16* l) {
    __builtin_amdgcn_global_load_lds(
        (const __attribute__((address_space(1))) void*)g,
        (__attribute__((address_space(3))) void*)l, 16, 0, 0);
}

// ---------------------------------------------------------------------------
// Wt[n][k] = bf16(W[k][n]) for 4 weights in one launch. N = K = 1280.
// ---------------------------------------------------------------------------
__global__ __launch_bounds__(256) void wtrans_kernel(
    const float* __restrict__ W0, const float* __restrict__ W1,
    const float* __restrict__ W2, const float* __restrict__ W3,
    u16* __restrict__ T0, u16* __restrict__ T1,
    u16* __restrict__ T2, u16* __restrict__ T3) {
    const int N = 1280;
    const int z = blockIdx.z;
    const float* W = (z == 0) ? W0 : (z == 1) ? W1 : (z == 2) ? W2 : W3;
    u16* T = (z == 0) ? T0 : (z == 1) ? T1 : (z == 2) ? T2 : T3;
    __shared__ float t[32][33];
    const int bx = blockIdx.x * 32, by = blockIdx.y * 32;
    const int x = threadIdx.x, ty = threadIdx.y;
#pragma unroll
    for (int j = 0; j < 4; j++) {
        const int y = ty + j * 8;
        t[y][x] = W[(size_t)(by + y) * N + (bx + x)];
    }
    __syncthreads();
#pragma unroll
    for (int j = 0; j < 4; j++) {
        const int y = ty + j * 8;
        T[(size_t)(bx + y) * N + (by + x)] = f2bf(t[x][y]);
    }
}

// ---------------------------------------------------------------------------
// fp32 -> bf16 convert, 8 elems/thread
// ---------------------------------------------------------------------------
__global__ __launch_bounds__(256) void conv_kernel(const float* __restrict__ in,
                                                   u16* __restrict__ out, int n8) {
    const int i = blockIdx.x * 256 + threadIdx.x;
    if (i >= n8) return;
    const float4 a = ((const float4*)in)[i * 2];
    const float4 b = ((const float4*)in)[i * 2 + 1];
    union { uint4 u; u16 s[8]; } cv;
    cv.s[0] = f2bf(a.x); cv.s[1] = f2bf(a.y); cv.s[2] = f2bf(a.z); cv.s[3] = f2bf(a.w);
    cv.s[4] = f2bf(b.x); cv.s[5] = f2bf(b.y); cv.s[6] = f2bf(b.z); cv.s[7] = f2bf(b.w);
    ((uint4*)out)[i] = cv.u;
}

// ---------------------------------------------------------------------------
// C[M,N] = A[M,K] @ Bt[N,K]^T, all bf16 in. m97-structure: global_load_lds
// staging into linear LDS, pre-swizzled source (chunk ^= row&7), swizzled
// ds_read_b128, double-buffered, one vmcnt(0)+barrier per K-tile.
// BM=BN=128, BK=64, 256 thr (4 waves, each 64x64 out).
// EPI: fp32 out = acc + bias + resid. TRANSC: Vt layout [(n>>11)*1280+m][n&2047].
// ---------------------------------------------------------------------------
template <bool TRANSC, bool EPI>
__global__ __launch_bounds__(256) void gemm2_kernel(
    const u16* __restrict__ A, const u16* __restrict__ Bt, void* __restrict__ Cp,
    const float* __restrict__ bias, const float* __restrict__ resid,
    const int M, const int N, const int K) {
    __shared__ __align__(16) u16 Al[2][128 * 64];
    __shared__ __align__(16) u16 Bl[2][128 * 64];
    const int tid = threadIdx.x;
    const int lane = tid & 63, w = tid >> 6;
    const int wr = w >> 1, wc = w & 1;
    const int lr = lane & 15, lq = lane >> 4;
    const int m0 = blockIdx.y * 128, n0 = blockIdx.x * 128;

    const int f_r = tid >> 3;                       // row for pass 0
    const int srcch = (tid & 7) ^ ((tid >> 3) & 7); // swizzled source chunk
    const int ldst = (tid & 192) * 8;               // wave-uniform LDS u16 base

    const f32x4 fzero = {0.f, 0.f, 0.f, 0.f};
    f32x4 acc[4][4];
#pragma unroll
    for (int i = 0; i < 4; i++)
#pragma unroll
        for (int j = 0; j < 4; j++) acc[i][j] = fzero;

    const int nkt = K >> 6;

#define STAGE(buf, kt)                                                          \
    {                                                                           \
        const int k0s = (kt) << 6;                                              \
        _Pragma("unroll")                                                       \
        for (int i = 0; i < 4; i++) {                                           \
            const int r = i * 32 + f_r;                                         \
            gll16(&A[(size_t)(m0 + r) * K + k0s + srcch * 8],                   \
                  &Al[buf][i * 2048 + ldst]);                                   \
            gll16(&Bt[(size_t)(n0 + r) * K + k0s + srcch * 8],                  \
                  &Bl[buf][i * 2048 + ldst]);                                   \
        }                                                                       \
    }

    STAGE(0, 0);
    asm volatile("s_waitcnt vmcnt(0)" ::: "memory");
    __syncthreads();
    int cur = 0;
    for (int kt = 0; kt < nkt; kt++) {
        if (kt + 1 < nkt) STAGE(cur ^ 1, kt + 1);
#pragma unroll
        for (int ks = 0; ks < 2; ks++) {
            bf16x8 af[4], bfv[4];
#pragma unroll
            for (int mi = 0; mi < 4; mi++) {
                const int rowA = wr * 64 + mi * 16 + lr;
                af[mi] = *(const bf16x8*)&Al[cur][rowA * 64 +
                                                  (((ks * 4 + lq) ^ (rowA & 7)) << 3)];
            }
#pragma unroll
            for (int ni = 0; ni < 4; ni++) {
                const int rowB = wc * 64 + ni * 16 + lr;
                bfv[ni] = *(const bf16x8*)&Bl[cur][rowB * 64 +
                                                   (((ks * 4 + lq) ^ (rowB & 7)) << 3)];
            }
#pragma unroll
            for (int mi = 0; mi < 4; mi++)
#pragma unroll
                for (int ni = 0; ni < 4; ni++)
                    acc[mi][ni] = MFMA(af[mi], bfv[ni], acc[mi][ni]);
        }
        asm volatile("s_waitcnt vmcnt(0)" ::: "memory");
        __syncthreads();
        cur ^= 1;
    }
#undef STAGE

#pragma unroll
    for (int mi = 0; mi < 4; mi++)
#pragma unroll
        for (int ni = 0; ni < 4; ni++)
#pragma unroll
            for (int j = 0; j < 4; j++) {
                const int row = m0 + wr * 64 + mi * 16 + lq * 4 + j;
                const int col = n0 + wc * 64 + ni * 16 + lr;
                const float v = acc[mi][ni][j];
                if (EPI) {
                    ((float*)Cp)[(size_t)row * N + col] =
                        v + bias[col] + resid[(size_t)row * N + col];
                } else if (TRANSC) {
                    ((u16*)Cp)[((size_t)(col >> 11) * 1280 + row) * 2048 +
                               (col & 2047)] = f2bf(v);
                } else {
                    ((u16*)Cp)[(size_t)row * N + col] = f2bf(v);
                }
            }
}

// ---------------------------------------------------------------------------
// Flash attention, KV-split-4 across blocks. Grid (16 qt, 8 h, 2b*4sp), 256 thr.
// Each block: 64 q-rows (wave wi owns 16), 8 K-tiles of 64 keys (kt=sp*8+t).
// K and V time-share one union LDS buffer; V reg-staged issue-early/write-late.
// Partials (m,l fp32; O bf16) to ws; merged by merge_kernel.
// ---------------------------------------------------------------------------
__global__ __launch_bounds__(256, 4) void attn_kernel(
    const u16* __restrict__ qb, const u16* __restrict__ kb,
    const u16* __restrict__ vtb, const int* __restrict__ seg,
    u16* __restrict__ op, float* __restrict__ mlp) {
    __shared__ __align__(16) u16 KV[11520];  // K [64][168] (10752) / Vt [160][72]
    __shared__ __align__(16) u16 Pl[64][72];
    __shared__ u8 segl[16][256];

    const int tid = threadIdx.x;
    const int lane = tid & 63, wi = tid >> 6;
    const int lr = lane & 15, lq = lane >> 4;
    const int qt = blockIdx.x, h = blockIdx.y;
    const int bz = blockIdx.z >> 2, sp = blockIdx.z & 3;
    const bool masked = (sp >= 2);

    if (masked) {
#pragma unroll
        for (int i = 0; i < 16; i++) {
            const int id = i * 256 + tid;
            segl[id >> 8][id & 255] =
                (u8)seg[(size_t)(bz * 256 + qt * 16 + (id >> 8)) * 256 + (id & 255)];
        }
    }

    bf16x8 qf[5];
    {
        const size_t grow = (size_t)(bz * 1024 + qt * 64 + wi * 16 + lr) * 1280 + h * 160;
#pragma unroll
        for (int ks = 0; ks < 5; ks++)
            qf[ks] = *(const bf16x8*)&qb[grow + ks * 32 + lq * 8];
    }

    // staging geometry (precomputed offsets)
    int kgo[5], klo[5], vgo[5], vlo[5];
#pragma unroll
    for (int i = 0; i < 5; i++) {
        const int id = i * 256 + tid;
        const int kr = id / 20, kc = id % 20;
        kgo[i] = kr * 1280 + h * 160 + kc * 8;
        klo[i] = kr * 168 + kc * 8;
        const int d = id >> 3, vc = id & 7;
        vgo[i] = (h * 160 + d) * 2048 + vc * 8;
        vlo[i] = d * 72 + vc * 8;
    }

    float m_i[4] = {0.f, 0.f, 0.f, 0.f}, l_i[4] = {0.f, 0.f, 0.f, 0.f};
    const f32x4 fzero = {0.f, 0.f, 0.f, 0.f};
    f32x4 oacc[10];
#pragma unroll
    for (int d = 0; d < 10; d++) oacc[d] = fzero;

    const float sc = 0.07905694150420949f;  // 1/sqrt(160)
    const size_t kbase = (size_t)bz * 2048 * 1280;
    const size_t vbase = (size_t)bz * 1280 * 2048;

    uint4 streg[5];
#pragma unroll
    for (int i = 0; i < 5; i++)  // prologue: K tile 0 of this split
        streg[i] = *(const uint4*)&kb[kbase + (size_t)(sp * 8) * 64 * 1280 + kgo[i]];

    for (int t = 0; t < 8; t++) {
        const int kt = sp * 8 + t;
        __syncthreads();  // all waves done reading V(t-1) (t=0: covers segl)
#pragma unroll
        for (int i = 0; i < 5; i++) *(uint4*)&KV[klo[i]] = streg[i];
        // issue V(t) loads (T14 issue-early; regs free after ds_write issues)
#pragma unroll
        for (int i = 0; i < 5; i++)
            streg[i] = *(const uint4*)&vtb[vbase + (size_t)kt * 64 + vgo[i]];
        __syncthreads();  // K visible

        // S = Q K^T (wave's 16 q-rows x 64 keys)
        f32x4 s4[4];
#pragma unroll
        for (int nt = 0; nt < 4; nt++) {
            s4[nt] = fzero;
#pragma unroll
            for (int ks = 0; ks < 5; ks++) {
                const bf16x8 bk = *(const bf16x8*)&KV[(nt * 16 + lr) * 168 + ks * 32 + lq * 8];
                s4[nt] = MFMA(qf[ks], bk, s4[nt]);
            }
        }
        // scale + mask (in place, s4 := p)
        const int q4 = wi * 4 + lq;
#pragma unroll
        for (int nt = 0; nt < 4; nt++) {
            float msk = 0.f;
            if (masked) {
                const int sg = (kt - 16) * 64 + nt * 16 + lr;
                if (!segl[q4][sg >> 2]) msk = -1e30f;
            }
#pragma unroll
            for (int j = 0; j < 4; j++) s4[nt][j] = s4[nt][j] * sc + msk;
        }
        // online softmax with defer-max (THR=8)
#pragma unroll
        for (int j = 0; j < 4; j++) {
            float rm = fmaxf(fmaxf(s4[0][j], s4[1][j]), fmaxf(s4[2][j], s4[3][j]));
            rm = fmaxf(rm, __shfl_xor(rm, 1));
            rm = fmaxf(rm, __shfl_xor(rm, 2));
            rm = fmaxf(rm, __shfl_xor(rm, 4));
            rm = fmaxf(rm, __shfl_xor(rm, 8));
            if (__any(rm > m_i[j] + 8.f)) {
                const float mn = fmaxf(m_i[j], rm);
                const float al = __expf(m_i[j] - mn);
                l_i[j] *= al;
                m_i[j] = mn;
#pragma unroll
                for (int d = 0; d < 10; d++) oacc[d][j] *= al;
            }
            float sum = 0.f;
#pragma unroll
            for (int nt = 0; nt < 4; nt++) {
                const float e = __expf(s4[nt][j] - m_i[j]);
                s4[nt][j] = e;
                sum += e;
            }
            sum += __shfl_xor(sum, 1);
            sum += __shfl_xor(sum, 2);
            sum += __shfl_xor(sum, 4);
            sum += __shfl_xor(sum, 8);
            l_i[j] += sum;
        }
        // P -> LDS (wave-private rows)
#pragma unroll
        for (int nt = 0; nt < 4; nt++)
#pragma unroll
            for (int j = 0; j < 4; j++)
                Pl[wi * 16 + lq * 4 + j][nt * 16 + lr] = f2bf(s4[nt][j]);

        __syncthreads();  // all waves done reading K
#pragma unroll
        for (int i = 0; i < 5; i++) *(uint4*)&KV[vlo[i]] = streg[i];  // waits vmcnt
        if (t + 1 < 8) {  // issue K(t+1)
#pragma unroll
            for (int i = 0; i < 5; i++)
                streg[i] = *(const uint4*)&kb[kbase + (size_t)(kt + 1) * 64 * 1280 + kgo[i]];
        }
        __syncthreads();  // V visible

        // O += P @ V
        bf16x8 pa[2];
#pragma unroll
        for (int ks2 = 0; ks2 < 2; ks2++)
            pa[ks2] = *(const bf16x8*)&Pl[wi * 16 + lr][ks2 * 32 + lq * 8];
#pragma unroll
        for (int nt2 = 0; nt2 < 10; nt2++)
#pragma unroll
            for (int ks2 = 0; ks2 < 2; ks2++) {
                const bf16x8 bv =
                    *(const bf16x8*)&KV[(nt2 * 16 + lr) * 72 + ks2 * 32 + lq * 8];
                oacc[nt2] = MFMA(pa[ks2], bv, oacc[nt2]);
            }
    }

    // write partials
    const size_t rbase = (size_t)sp * 2048 + bz * 1024 + qt * 64 + wi * 16;
#pragma unroll
    for (int j = 0; j < 4; j++) {
        const size_t r = rbase + lq * 4 + j;
        if (lr == 0) {
            mlp[(r * 8 + h) * 2 + 0] = m_i[j];
            mlp[(r * 8 + h) * 2 + 1] = l_i[j];
        }
#pragma unroll
        for (int nt2 = 0; nt2 < 10; nt2++)
            op[r * 1280 + h * 160 + nt2 * 16 + lr] = f2bf(oacc[nt2][j]);
    }
}

// ---------------------------------------------------------------------------
// merge 4 KV-split partials -> aobuf bf16 [2048][1280]
// ---------------------------------------------------------------------------
__global__ __launch_bounds__(256) void merge_kernel(const u16* __restrict__ op,
                                                    const float* __restrict__ mlp,
                                                    u16* __restrict__ ao) {
    const int c = blockIdx.x * 256 + threadIdx.x;  // 0..1279
    const int r = blockIdx.y;                      // 0..2047
    const int h = c / 160;
    float m[4], l[4];
#pragma unroll
    for (int s = 0; s < 4; s++) {
        m[s] = mlp[(((size_t)s * 2048 + r) * 8 + h) * 2];
        l[s] = mlp[(((size_t)s * 2048 + r) * 8 + h) * 2 + 1];
    }
    const float M = fmaxf(fmaxf(m[0], m[1]), fmaxf(m[2], m[3]));
    float num = 0.f, den = 0.f;
#pragma unroll
    for (int s = 0; s < 4; s++) {
        const float e = __expf(m[s] - M);
        den += l[s] * e;
        num += bf2f(op[((size_t)s * 2048 + r) * 1280 + c]) * e;
    }
    ao[(size_t)r * 1280 + c] = f2bf(num / den);
}

// ---------------------------------------------------------------------------
extern "C" void kernel_launch(void* const* d_in, const int* in_sizes, int n_in,
                              void* d_out, int out_size, void* d_ws, size_t ws_size,
                              hipStream_t stream) {
    const float* hs  = (const float*)d_in[0];
    const float* ehs = (const float*)d_in[1];
    const int*   seg = (const int*)d_in[2];
    const float* Wq  = (const float*)d_in[3];
    const float* Wk  = (const float*)d_in[4];
    const float* Wv  = (const float*)d_in[5];
    const float* Wo  = (const float*)d_in[6];
    const float* bo  = (const float*)d_in[7];
    float* out = (float*)d_out;

    // ws layout (u16 units); opart overlays hbuf..WvT (all dead before attn),
    // aobuf overlays qbuf (dead after attn). Total 55.05 MB.
    u16* base  = (u16*)d_ws;
    u16* WoT   = base;                  // 1,638,400
    u16* qbuf  = WoT + 1638400;         // 2,621,440
    u16* kbuf  = qbuf + 2621440;        // 5,242,880
    u16* vtbuf = kbuf + 5242880;        // 5,242,880
    u16* hbuf  = vtbuf + 5242880;       // 2,621,440
    u16* ebuf  = hbuf + 2621440;        // 5,242,880
    u16* WqT   = ebuf + 5242880;        // 1,638,400
    u16* WkT   = WqT + 1638400;         // 1,638,400
    u16* WvT   = WkT + 1638400;         // 1,638,400
    u16* opart = hbuf;                  // 10,485,760 (overlay)
    float* mlpart = (float*)(opart + 10485760);  // 131,072 f32 (in WkT region)
    u16* aobuf = qbuf;                  // overlay

    dim3 tb(32, 8), tg(40, 40, 4);
    wtrans_kernel<<<tg, tb, 0, stream>>>(Wq, Wk, Wv, Wo, WqT, WkT, WvT, WoT);
    conv_kernel<<<1280, 256, 0, stream>>>(hs, hbuf, 327680);
    conv_kernel<<<2560, 256, 0, stream>>>(ehs, ebuf, 655360);

    gemm2_kernel<false, false><<<dim3(10, 16), 256, 0, stream>>>(
        hbuf, WqT, qbuf, nullptr, nullptr, 2048, 1280, 1280);
    gemm2_kernel<false, false><<<dim3(10, 32), 256, 0, stream>>>(
        ebuf, WkT, kbuf, nullptr, nullptr, 4096, 1280, 1280);
    gemm2_kernel<true, false><<<dim3(32, 10), 256, 0, stream>>>(
        WvT, ebuf, vtbuf, nullptr, nullptr, 1280, 4096, 1280);

    attn_kernel<<<dim3(16, 8, 8), 256, 0, stream>>>(qbuf, kbuf, vtbuf, seg,
                                                    opart, mlpart);
    merge_kernel<<<dim3(5, 2048), 256, 0, stream>>>(opart, mlpart, aobuf);

    gemm2_kernel<false, true><<<dim3(10, 16), 256, 0, stream>>>(
        aobuf, WoT, out, bo, hs, 2048, 1280, 1280);
}